// Round 10
// baseline (115.231 us; speedup 1.0000x reference)
//
#include <hip/hip_runtime.h>

#define B_ 32
#define Q_ 16
#define D_ 2048
#define E_ 300
#define EF4 75              // float4s per embedding row
#define NB 30
#define TILE 128            // doc rows per block (2 per lane)
#define TPB (D_ / TILE)     // tiles per batch = 16

// Hardware-TRANS-pipe transcendentals (R2 post-mortem: ocml tanhf/log1pf left
// drmm_final 99% stalled).
__device__ __forceinline__ float fast_tanh(float x) {
    const float t = __expf(-2.0f * fabsf(x));      // (0,1], never overflows
    const float r = (1.0f - t) / (1.0f + t);
    return copysignf(r, x);
}
__device__ __forceinline__ float fast_log1p(float x) {   // x >= 0 here
    return __logf(1.0f + x);
}

// ---------------- Kernel 1: query prep (qn, gate logits) + hist zero ----------------
__global__ __launch_bounds__(256) void drmm_prep(
    const int* __restrict__ query, const float* __restrict__ emb,
    const float* __restrict__ Wg, const float* __restrict__ bg,
    float* __restrict__ qn, float* __restrict__ gbuf, int* __restrict__ hist)
{
    const int b = blockIdx.x, tid = threadIdx.x;
    const int wid = tid >> 6, lane = tid & 63;

    for (int i = b * 256 + tid; i < B_ * Q_ * NB; i += B_ * 256) hist[i] = 0;

    for (int qq = wid; qq < Q_; qq += 4) {
        const int id = query[b * Q_ + qq];
        const float m = (id > 0) ? 1.f : 0.f;
        const float* row = emb + (long long)((id > 0) ? id : 0) * E_;
        float v[5];
        float ss = 0.f, dg = 0.f;
        #pragma unroll
        for (int k = 0; k < 5; ++k) {
            const int e = lane + 64 * k;
            float x = 0.f, w = 0.f;
            if (e < E_) { x = row[e] * m; w = Wg[e]; }
            v[k] = x;
            ss = fmaf(x, x, ss);
            dg = fmaf(x, w, dg);
        }
        #pragma unroll
        for (int off = 32; off > 0; off >>= 1) {
            ss += __shfl_xor(ss, off);
            dg += __shfl_xor(dg, off);
        }
        // masked row: ss==0 -> rn=inf -> qn = 0*inf = NaN, matching reference 0/0
        const float rn = 1.0f / sqrtf(ss);
        #pragma unroll
        for (int k = 0; k < 5; ++k) {
            const int e = lane + 64 * k;
            if (e < E_) qn[((size_t)(b * Q_ + qq)) * E_ + e] = v[k] * rn;
        }
        if (lane == 0) gbuf[b * Q_ + qq] = fast_tanh(dg + bg[0]);
    }
}

// Sub-burst window: load N consecutive float4s of BOTH rows into registers
// (2N loads in flight; 16N consecutive bytes per row -> L2 sectors consumed
// immediately), then the FMA block. All indices compile-time (R7 lesson).
template<int N>
__device__ __forceinline__ void chunk(const float4* __restrict__ rA,
                                      const float4* __restrict__ rB,
                                      const float4* __restrict__ qs4c,
                                      int kbase,
                                      float* __restrict__ accA,
                                      float* __restrict__ accB,
                                      float& ssA, float& ssB)
{
    float4 va[N], vb[N];
    #pragma unroll
    for (int k = 0; k < N; ++k) { va[k] = rA[kbase + k]; vb[k] = rB[kbase + k]; }
    #pragma unroll
    for (int k = 0; k < N; ++k) {
        const float4 a = va[k], c = vb[k];
        ssA = fmaf(a.x, a.x, fmaf(a.y, a.y, fmaf(a.z, a.z, fmaf(a.w, a.w, ssA))));
        ssB = fmaf(c.x, c.x, fmaf(c.y, c.y, fmaf(c.z, c.z, fmaf(c.w, c.w, ssB))));
        #pragma unroll
        for (int q = 0; q < Q_; ++q) {
            const float4 u = qs4c[q * EF4 + kbase + k];   // wave-uniform broadcast
            accA[q] = fmaf(a.x, u.x, fmaf(a.y, u.y, fmaf(a.z, u.z, fmaf(a.w, u.w, accA[q]))));
            accB[q] = fmaf(c.x, u.x, fmaf(c.y, u.y, fmaf(c.z, u.z, fmaf(c.w, u.w, accB[q]))));
        }
    }
}

// ---------------- Kernel 2: interaction dots + histogram ----------------
// Block = 128 doc rows, 2 per lane; 4 waves split E {19,19,19,18} float4s.
// R9 post-mortem: 49MB FETCH (bursts work) but VGPR 184 (merged burst windows)
// + 56KB LDS (2 blocks/CU) -> 8 lock-step waves/CU, latency-bound at 0.6TB/s.
// Fixes: (a) bursts of 4 float4 with sched_barrier(0) between windows ->
// ~32 buffer VGPRs, no window merging; (b) two-phase cross-wave reduction
// (part[4][9][128] reused for q0-7 then q8-15) -> LDS 39.6KB -> 4 blocks/CU
// = 16 waves. Occupancy hides the per-window latency; bursts keep bytes low.
__global__ __launch_bounds__(256, 4) void drmm_main(
    const int* __restrict__ doc, const float* __restrict__ emb,
    const float* __restrict__ qn, int* __restrict__ hist)
{
    __shared__ __align__(16) float qs[Q_ * E_];      // 19200 B
    __shared__ float part[4][9][TILE];               // 18432 B (q-half + ss)
    __shared__ int   whist[Q_ * NB];                 // 1920 B

    const int tid = threadIdx.x;
    // XCD-grouped decode: xcd = blk&7 hosts batches {xcd, 8+xcd, 16+xcd, 24+xcd}
    const int blk = blockIdx.x;                      // 0..511
    const int xcd = blk & 7;
    const int j   = blk >> 3;                        // 0..63
    const int b   = ((j & 3) << 3) | xcd;            // 0..31
    const int tile = j >> 2;                         // 0..15
    const int lane = tid & 63, w = tid >> 6;

    // stage qn tile (one coalesced burst) + zero block histogram
    const float4* qb = (const float4*)(qn + (size_t)b * Q_ * E_);
    float4* qs4w = (float4*)qs;
    for (int i = tid; i < Q_ * EF4; i += 256) qs4w[i] = qb[i];
    for (int i = tid; i < Q_ * NB; i += 256) whist[i] = 0;
    __syncthreads();

    const int dbase = b * D_ + tile * TILE + lane;
    const int idA = doc[dbase];
    const int idB = doc[dbase + 64];
    const bool okA = (idA > 0), okB = (idB > 0);
    const int cbeg = w * 19;                 // chunks: 19,19,19,18 float4s
    const float4* rA = ((const float4*)(emb + (long long)(okA ? idA : 0) * E_)) + cbeg;
    const float4* rB = ((const float4*)(emb + (long long)(okB ? idB : 0) * E_)) + cbeg;
    const float4* qs4c = (const float4*)qs + cbeg;

    float accA[Q_], accB[Q_];
    #pragma unroll
    for (int q = 0; q < Q_; ++q) { accA[q] = 0.f; accB[q] = 0.f; }
    float ssA = 0.f, ssB = 0.f;

    // burst windows of 4 float4 (64B/row): waves 0-2: 4+4+4+4+3; wave 3: 4+4+4+3+3.
    // sched_barrier(0) pins each window (R9: merged windows -> VGPR 184).
    chunk<4>(rA, rB, qs4c, 0, accA, accB, ssA, ssB);
    __builtin_amdgcn_sched_barrier(0);
    chunk<4>(rA, rB, qs4c, 4, accA, accB, ssA, ssB);
    __builtin_amdgcn_sched_barrier(0);
    chunk<4>(rA, rB, qs4c, 8, accA, accB, ssA, ssB);
    __builtin_amdgcn_sched_barrier(0);
    if (w < 3) {                              // wave-uniform branch
        chunk<4>(rA, rB, qs4c, 12, accA, accB, ssA, ssB);
        __builtin_amdgcn_sched_barrier(0);
        chunk<3>(rA, rB, qs4c, 16, accA, accB, ssA, ssB);
    } else {
        chunk<3>(rA, rB, qs4c, 12, accA, accB, ssA, ssB);
        __builtin_amdgcn_sched_barrier(0);
        chunk<3>(rA, rB, qs4c, 15, accA, accB, ssA, ssB);
    }

    // -------- two-phase cross-wave reduction (halved part[] -> 4 blocks/CU) ----
    // phase 0: q 0..7 (+ sumsq in slot 8)
    #pragma unroll
    for (int q = 0; q < 8; ++q) {
        part[w][q][lane]      = accA[q];
        part[w][q][lane + 64] = accB[q];
    }
    part[w][8][lane]      = ssA;
    part[w][8][lane + 64] = ssB;
    __syncthreads();

    const int r  = tid & 127;
    const int h  = tid >> 7;                 // 0/1: which 4-q group
    const float sst = part[0][8][r] + part[1][8][r]
                    + part[2][8][r] + part[3][8][r];
    const float rn = 1.0f / sqrtf(sst);      // zeros -> inf -> NaN sims -> dropped
    const bool rok = (doc[b * D_ + tile * TILE + r] > 0);

    #pragma unroll
    for (int qq = 0; qq < 4; ++qq) {
        const int qsl = h * 4 + qq;          // slot & global q (phase 0)
        const float s = part[0][qsl][r] + part[1][qsl][r]
                      + part[2][qsl][r] + part[3][qsl][r];
        const float x = s * rn;              // NaN (masked q row) -> dropped
        const float t = (x + 1.0f) * (NB * 0.5f);
        int bin = (int)floorf(t);
        bin = bin < 0 ? 0 : (bin > NB - 1 ? NB - 1 : bin);
        if (rok && x >= -1.0f && x <= 1.0f)
            atomicAdd(&whist[qsl * NB + bin], 1);
    }
    __syncthreads();                          // phase-0 reads done

    // phase 1: q 8..15 into slots 0..7 (slot 8 / ss untouched)
    #pragma unroll
    for (int q = 0; q < 8; ++q) {
        part[w][q][lane]      = accA[8 + q];
        part[w][q][lane + 64] = accB[8 + q];
    }
    __syncthreads();

    #pragma unroll
    for (int qq = 0; qq < 4; ++qq) {
        const int qsl = h * 4 + qq;
        const float s = part[0][qsl][r] + part[1][qsl][r]
                      + part[2][qsl][r] + part[3][qsl][r];
        const float x = s * rn;
        const float t = (x + 1.0f) * (NB * 0.5f);
        int bin = (int)floorf(t);
        bin = bin < 0 ? 0 : (bin > NB - 1 ? NB - 1 : bin);
        if (rok && x >= -1.0f && x <= 1.0f)
            atomicAdd(&whist[(8 + qsl) * NB + bin], 1);
    }
    __syncthreads();

    // flush block histogram to global
    for (int i = tid; i < Q_ * NB; i += 256) {
        const int v = whist[i];
        if (v) atomicAdd(&hist[b * Q_ * NB + i], v);
    }
}

// ---------------- Kernel 3: log1p + FFN + gated sum ----------------
__global__ __launch_bounds__(64) void drmm_final(
    const int* __restrict__ hist, const float* __restrict__ gbuf,
    const int* __restrict__ query,
    const float* __restrict__ W1, const float* __restrict__ b1,
    const float* __restrict__ W2, const float* __restrict__ b2,
    const float* __restrict__ W3, const float* __restrict__ b3,
    float* __restrict__ out)
{
    const int b = blockIdx.x, lane = threadIdx.x;
    float z = 0.f, e = 0.f;
    if (lane < Q_) {
        const int* h = hist + (b * Q_ + lane) * NB;
        float pre1[5];
        #pragma unroll
        for (int u = 0; u < 5; ++u) pre1[u] = b1[u];
        #pragma unroll
        for (int k = 0; k < NB; ++k) {
            const float hv = fast_log1p((float)h[k]);
            #pragma unroll
            for (int u = 0; u < 5; ++u) pre1[u] = fmaf(hv, W1[k * 5 + u], pre1[u]);
        }
        float z2 = b2[0];
        #pragma unroll
        for (int u = 0; u < 5; ++u) z2 = fmaf(fast_tanh(pre1[u]), W2[u], z2);
        const float z3 = fmaf(fast_tanh(z2), W3[0], b3[0]);
        z = fast_tanh(z3);
        const int id = query[b * Q_ + lane];
        const float g = gbuf[b * Q_ + lane];
        e = (id > 0) ? __expf(g) : 0.f;
    }
    float ze = z * e, se = e;
    #pragma unroll
    for (int off = 32; off > 0; off >>= 1) {
        ze += __shfl_xor(ze, off);
        se += __shfl_xor(se, off);
    }
    if (lane == 0) out[b] = ze / (se + 1e-5f);
}

// ---------------- launch ----------------
extern "C" void kernel_launch(void* const* d_in, const int* in_sizes, int n_in,
                              void* d_out, int out_size, void* d_ws, size_t ws_size,
                              hipStream_t stream)
{
    const int*   query = (const int*)d_in[0];
    const int*   doc   = (const int*)d_in[1];
    // d_in[2] = q_idf (unused by reference)
    const float* emb   = (const float*)d_in[3];
    const float* W1    = (const float*)d_in[4];
    const float* b1    = (const float*)d_in[5];
    const float* W2    = (const float*)d_in[6];
    const float* b2    = (const float*)d_in[7];
    const float* W3    = (const float*)d_in[8];
    const float* b3    = (const float*)d_in[9];
    const float* Wg    = (const float*)d_in[10];
    const float* bg    = (const float*)d_in[11];
    float* out = (float*)d_out;

    // workspace layout
    char* ws = (char*)d_ws;
    float* qn   = (float*)ws;                        // 512*300 f32 = 614400 B
    float* gbuf = (float*)(ws + 614400);             // 512 f32    = 2048 B
    int*   hist = (int*)(ws + 614400 + 2048);        // 15360 ints = 61440 B

    drmm_prep<<<B_, 256, 0, stream>>>(query, emb, Wg, bg, qn, gbuf, hist);
    drmm_main<<<B_ * TPB, 256, 0, stream>>>(doc, emb, qn, hist);
    drmm_final<<<B_, 64, 0, stream>>>(hist, gbuf, query,
                                      W1, b1, W2, b2, W3, b3, out);
}

// Round 11
// 103.821 us; speedup vs baseline: 1.1099x; 1.1099x over previous
//
#include <hip/hip_runtime.h>

#define B_ 32
#define Q_ 16
#define D_ 2048
#define E_ 300
#define EF4 75              // float4s per embedding row
#define NB 30
#define TILE 128            // doc rows per block (2 per lane)
#define TPB (D_ / TILE)     // tiles per batch = 16

// Hardware-TRANS-pipe transcendentals (R2 post-mortem: ocml tanhf/log1pf left
// drmm_final 99% stalled).
__device__ __forceinline__ float fast_tanh(float x) {
    const float t = __expf(-2.0f * fabsf(x));      // (0,1], never overflows
    const float r = (1.0f - t) / (1.0f + t);
    return copysignf(r, x);
}
__device__ __forceinline__ float fast_log1p(float x) {   // x >= 0 here
    return __logf(1.0f + x);
}

// ---------------- Kernel 1: query prep (qn, gate logits) + hist zero ----------------
__global__ __launch_bounds__(256) void drmm_prep(
    const int* __restrict__ query, const float* __restrict__ emb,
    const float* __restrict__ Wg, const float* __restrict__ bg,
    float* __restrict__ qn, float* __restrict__ gbuf, int* __restrict__ hist)
{
    const int b = blockIdx.x, tid = threadIdx.x;
    const int wid = tid >> 6, lane = tid & 63;

    for (int i = b * 256 + tid; i < B_ * Q_ * NB; i += B_ * 256) hist[i] = 0;

    for (int qq = wid; qq < Q_; qq += 4) {
        const int id = query[b * Q_ + qq];
        const float m = (id > 0) ? 1.f : 0.f;
        const float* row = emb + (long long)((id > 0) ? id : 0) * E_;
        float v[5];
        float ss = 0.f, dg = 0.f;
        #pragma unroll
        for (int k = 0; k < 5; ++k) {
            const int e = lane + 64 * k;
            float x = 0.f, w = 0.f;
            if (e < E_) { x = row[e] * m; w = Wg[e]; }
            v[k] = x;
            ss = fmaf(x, x, ss);
            dg = fmaf(x, w, dg);
        }
        #pragma unroll
        for (int off = 32; off > 0; off >>= 1) {
            ss += __shfl_xor(ss, off);
            dg += __shfl_xor(dg, off);
        }
        // masked row: ss==0 -> rn=inf -> qn = 0*inf = NaN, matching reference 0/0
        const float rn = 1.0f / sqrtf(ss);
        #pragma unroll
        for (int k = 0; k < 5; ++k) {
            const int e = lane + 64 * k;
            if (e < E_) qn[((size_t)(b * Q_ + qq)) * E_ + e] = v[k] * rn;
        }
        if (lane == 0) gbuf[b * Q_ + qq] = fast_tanh(dg + bg[0]);
    }
}

// Burst window: load N consecutive float4s of BOTH rows into registers
// (2N loads issued together; 16N consecutive bytes per row -> L2 lines
// consumed immediately), then the FMA block. Indices static after inlining
// (R7 lesson); kbase may be runtime.
template<int N>
__device__ __forceinline__ void chunk(const float4* __restrict__ rA,
                                      const float4* __restrict__ rB,
                                      const float4* __restrict__ qs4c,
                                      int kbase,
                                      float* __restrict__ accA,
                                      float* __restrict__ accB,
                                      float& ssA, float& ssB)
{
    float4 va[N], vb[N];
    #pragma unroll
    for (int k = 0; k < N; ++k) { va[k] = rA[kbase + k]; vb[k] = rB[kbase + k]; }
    #pragma unroll
    for (int k = 0; k < N; ++k) {
        const float4 a = va[k], c = vb[k];
        ssA = fmaf(a.x, a.x, fmaf(a.y, a.y, fmaf(a.z, a.z, fmaf(a.w, a.w, ssA))));
        ssB = fmaf(c.x, c.x, fmaf(c.y, c.y, fmaf(c.z, c.z, fmaf(c.w, c.w, ssB))));
        #pragma unroll
        for (int q = 0; q < Q_; ++q) {
            const float4 u = qs4c[q * EF4 + kbase + k];   // wave-uniform broadcast
            accA[q] = fmaf(a.x, u.x, fmaf(a.y, u.y, fmaf(a.z, u.z, fmaf(a.w, u.w, accA[q]))));
            accB[q] = fmaf(c.x, u.x, fmaf(c.y, u.y, fmaf(c.z, u.z, fmaf(c.w, u.w, accB[q]))));
        }
    }
}

// ---------------- Kernel 2: interaction dots + histogram ----------------
// Block = 128 doc rows, 2 per lane; 4 waves split E {19,19,19,18} float4s.
// Synthesis of R8/R9/R10 post-mortems:
//  - bytes need bursts  (R9: 49MB with grouped loads vs R8: 117MB trickled)
//  - rate needs waves   (R8: 2.4TB/s @6 waves/CU vs R9: 0.6TB/s @3.5)
//  - spill-freedom needs bounded windows, NOT sched_barrier (R10: allocator
//    meltdown, VGPR 64 + 189MB scratch)
// Fix: '#pragma unroll 1' RUNTIME loop over 4 windows of 4 float4/row — the
// loop back-edge stops cross-window load merging (buffers capped at 32 VGPR)
// while each window's 8 loads issue together. Two-phase part[] reduction
// keeps LDS at 39.9KB -> 4 blocks/CU = 16 waves/CU.
__global__ __launch_bounds__(256, 4) void drmm_main(
    const int* __restrict__ doc, const float* __restrict__ emb,
    const float* __restrict__ qn, int* __restrict__ hist)
{
    __shared__ __align__(16) float qs[Q_ * E_];      // 19200 B
    __shared__ float part[4][9][TILE];               // 18432 B (q-half + ss)
    __shared__ int   whist[Q_ * NB];                 // 1920 B

    const int tid = threadIdx.x;
    // XCD-grouped decode: xcd = blk&7 hosts batches {xcd, 8+xcd, 16+xcd, 24+xcd}
    const int blk = blockIdx.x;                      // 0..511
    const int xcd = blk & 7;
    const int j   = blk >> 3;                        // 0..63
    const int b   = ((j & 3) << 3) | xcd;            // 0..31
    const int tile = j >> 2;                         // 0..15
    const int lane = tid & 63, w = tid >> 6;

    // stage qn tile (one coalesced burst) + zero block histogram
    const float4* qb = (const float4*)(qn + (size_t)b * Q_ * E_);
    float4* qs4w = (float4*)qs;
    for (int i = tid; i < Q_ * EF4; i += 256) qs4w[i] = qb[i];
    for (int i = tid; i < Q_ * NB; i += 256) whist[i] = 0;
    __syncthreads();

    const int dbase = b * D_ + tile * TILE + lane;
    const int idA = doc[dbase];
    const int idB = doc[dbase + 64];
    const bool okA = (idA > 0), okB = (idB > 0);
    const int cbeg = w * 19;                 // chunks: 19,19,19,18 float4s
    const float4* rA = ((const float4*)(emb + (long long)(okA ? idA : 0) * E_)) + cbeg;
    const float4* rB = ((const float4*)(emb + (long long)(okB ? idB : 0) * E_)) + cbeg;
    const float4* qs4c = (const float4*)qs + cbeg;

    float accA[Q_], accB[Q_];
    #pragma unroll
    for (int q = 0; q < Q_; ++q) { accA[q] = 0.f; accB[q] = 0.f; }
    float ssA = 0.f, ssB = 0.f;

    // 4 burst windows of 4 float4 (64B/row each), runtime loop, NOT unrolled:
    // the back-edge bounds buffer live ranges to one window.
    #pragma unroll 1
    for (int win = 0; win < 4; ++win) {
        chunk<4>(rA, rB, qs4c, win * 4, accA, accB, ssA, ssB);
    }
    // tail: waves 0-2 have 3 more (19 total), wave 3 has 2 more (18 total)
    if (w < 3) chunk<3>(rA, rB, qs4c, 16, accA, accB, ssA, ssB);
    else       chunk<2>(rA, rB, qs4c, 16, accA, accB, ssA, ssB);

    // -------- two-phase cross-wave reduction (halved part[] -> 4 blocks/CU) ----
    // phase 0: q 0..7 (+ sumsq in slot 8)
    #pragma unroll
    for (int q = 0; q < 8; ++q) {
        part[w][q][lane]      = accA[q];
        part[w][q][lane + 64] = accB[q];
    }
    part[w][8][lane]      = ssA;
    part[w][8][lane + 64] = ssB;
    __syncthreads();

    const int r  = tid & 127;
    const int h  = tid >> 7;                 // 0/1: which 4-q group
    const float sst = part[0][8][r] + part[1][8][r]
                    + part[2][8][r] + part[3][8][r];
    const float rn = 1.0f / sqrtf(sst);      // zeros -> inf -> NaN sims -> dropped
    const bool rok = (doc[b * D_ + tile * TILE + r] > 0);

    #pragma unroll
    for (int qq = 0; qq < 4; ++qq) {
        const int qsl = h * 4 + qq;          // slot & global q (phase 0)
        const float s = part[0][qsl][r] + part[1][qsl][r]
                      + part[2][qsl][r] + part[3][qsl][r];
        const float x = s * rn;              // NaN (masked q row) -> dropped
        const float t = (x + 1.0f) * (NB * 0.5f);
        int bin = (int)floorf(t);
        bin = bin < 0 ? 0 : (bin > NB - 1 ? NB - 1 : bin);
        if (rok && x >= -1.0f && x <= 1.0f)
            atomicAdd(&whist[qsl * NB + bin], 1);
    }
    __syncthreads();                          // phase-0 reads done

    // phase 1: q 8..15 into slots 0..7 (slot 8 / ss untouched)
    #pragma unroll
    for (int q = 0; q < 8; ++q) {
        part[w][q][lane]      = accA[8 + q];
        part[w][q][lane + 64] = accB[8 + q];
    }
    __syncthreads();

    #pragma unroll
    for (int qq = 0; qq < 4; ++qq) {
        const int qsl = h * 4 + qq;
        const float s = part[0][qsl][r] + part[1][qsl][r]
                      + part[2][qsl][r] + part[3][qsl][r];
        const float x = s * rn;
        const float t = (x + 1.0f) * (NB * 0.5f);
        int bin = (int)floorf(t);
        bin = bin < 0 ? 0 : (bin > NB - 1 ? NB - 1 : bin);
        if (rok && x >= -1.0f && x <= 1.0f)
            atomicAdd(&whist[(8 + qsl) * NB + bin], 1);
    }
    __syncthreads();

    // flush block histogram to global
    for (int i = tid; i < Q_ * NB; i += 256) {
        const int v = whist[i];
        if (v) atomicAdd(&hist[b * Q_ * NB + i], v);
    }
}

// ---------------- Kernel 3: log1p + FFN + gated sum ----------------
__global__ __launch_bounds__(64) void drmm_final(
    const int* __restrict__ hist, const float* __restrict__ gbuf,
    const int* __restrict__ query,
    const float* __restrict__ W1, const float* __restrict__ b1,
    const float* __restrict__ W2, const float* __restrict__ b2,
    const float* __restrict__ W3, const float* __restrict__ b3,
    float* __restrict__ out)
{
    const int b = blockIdx.x, lane = threadIdx.x;
    float z = 0.f, e = 0.f;
    if (lane < Q_) {
        const int* h = hist + (b * Q_ + lane) * NB;
        float pre1[5];
        #pragma unroll
        for (int u = 0; u < 5; ++u) pre1[u] = b1[u];
        #pragma unroll
        for (int k = 0; k < NB; ++k) {
            const float hv = fast_log1p((float)h[k]);
            #pragma unroll
            for (int u = 0; u < 5; ++u) pre1[u] = fmaf(hv, W1[k * 5 + u], pre1[u]);
        }
        float z2 = b2[0];
        #pragma unroll
        for (int u = 0; u < 5; ++u) z2 = fmaf(fast_tanh(pre1[u]), W2[u], z2);
        const float z3 = fmaf(fast_tanh(z2), W3[0], b3[0]);
        z = fast_tanh(z3);
        const int id = query[b * Q_ + lane];
        const float g = gbuf[b * Q_ + lane];
        e = (id > 0) ? __expf(g) : 0.f;
    }
    float ze = z * e, se = e;
    #pragma unroll
    for (int off = 32; off > 0; off >>= 1) {
        ze += __shfl_xor(ze, off);
        se += __shfl_xor(se, off);
    }
    if (lane == 0) out[b] = ze / (se + 1e-5f);
}

// ---------------- launch ----------------
extern "C" void kernel_launch(void* const* d_in, const int* in_sizes, int n_in,
                              void* d_out, int out_size, void* d_ws, size_t ws_size,
                              hipStream_t stream)
{
    const int*   query = (const int*)d_in[0];
    const int*   doc   = (const int*)d_in[1];
    // d_in[2] = q_idf (unused by reference)
    const float* emb   = (const float*)d_in[3];
    const float* W1    = (const float*)d_in[4];
    const float* b1    = (const float*)d_in[5];
    const float* W2    = (const float*)d_in[6];
    const float* b2    = (const float*)d_in[7];
    const float* W3    = (const float*)d_in[8];
    const float* b3    = (const float*)d_in[9];
    const float* Wg    = (const float*)d_in[10];
    const float* bg    = (const float*)d_in[11];
    float* out = (float*)d_out;

    // workspace layout
    char* ws = (char*)d_ws;
    float* qn   = (float*)ws;                        // 512*300 f32 = 614400 B
    float* gbuf = (float*)(ws + 614400);             // 512 f32    = 2048 B
    int*   hist = (int*)(ws + 614400 + 2048);        // 15360 ints = 61440 B

    drmm_prep<<<B_, 256, 0, stream>>>(query, emb, Wg, bg, qn, gbuf, hist);
    drmm_main<<<B_ * TPB, 256, 0, stream>>>(doc, emb, qn, hist);
    drmm_final<<<B_, 64, 0, stream>>>(hist, gbuf, query,
                                      W1, b1, W2, b2, W3, b3, out);
}

// Round 12
// 70.090 us; speedup vs baseline: 1.6440x; 1.4812x over previous
//
#include <hip/hip_runtime.h>

#define B_ 32
#define Q_ 16
#define D_ 2048
#define E_ 300
#define EF4 75              // float4 granules per embedding row
#define NB 30
#define TR 32               // doc rows per block
#define PITCH 77            // LDS granules per row (77%8=5, gcd 1 -> bank spread)
#define TPB (D_ / TR)       // 64 tiles per batch

// Hardware-TRANS-pipe transcendentals (R2: ocml tanhf/log1pf left final 99% stalled)
__device__ __forceinline__ float fast_tanh(float x) {
    const float t = __expf(-2.0f * fabsf(x));
    const float r = (1.0f - t) / (1.0f + t);
    return copysignf(r, x);
}
__device__ __forceinline__ float fast_log1p(float x) { return __logf(1.0f + x); }

// ---------------- Kernel 1: query prep (qn, gate logits) + hist zero ----------------
__global__ __launch_bounds__(256) void drmm_prep(
    const int* __restrict__ query, const float* __restrict__ emb,
    const float* __restrict__ Wg, const float* __restrict__ bg,
    float* __restrict__ qn, float* __restrict__ gbuf, int* __restrict__ hist)
{
    const int b = blockIdx.x, tid = threadIdx.x;
    const int wid = tid >> 6, lane = tid & 63;

    for (int i = b * 256 + tid; i < B_ * Q_ * NB; i += B_ * 256) hist[i] = 0;

    for (int qq = wid; qq < Q_; qq += 4) {
        const int id = query[b * Q_ + qq];
        const float m = (id > 0) ? 1.f : 0.f;
        const float* row = emb + (long long)((id > 0) ? id : 0) * E_;
        float v[5];
        float ss = 0.f, dg = 0.f;
        #pragma unroll
        for (int k = 0; k < 5; ++k) {
            const int e = lane + 64 * k;
            float x = 0.f, w = 0.f;
            if (e < E_) { x = row[e] * m; w = Wg[e]; }
            v[k] = x;
            ss = fmaf(x, x, ss);
            dg = fmaf(x, w, dg);
        }
        #pragma unroll
        for (int off = 32; off > 0; off >>= 1) {
            ss += __shfl_xor(ss, off);
            dg += __shfl_xor(dg, off);
        }
        // masked row: ss==0 -> rn=inf -> qn = 0*inf = NaN (matches reference 0/0)
        const float rn = 1.0f / sqrtf(ss);
        #pragma unroll
        for (int k = 0; k < 5; ++k) {
            const int e = lane + 64 * k;
            if (e < E_) qn[((size_t)(b * Q_ + qq)) * E_ + e] = v[k] * rn;
        }
        if (lane == 0) gbuf[b * Q_ + qq] = fast_tanh(dg + bg[0]);
    }
}

// ---------------- Kernel 2: interaction dots + histogram ----------------
// R6-R11 post-mortems: the 2-row/lane register-tiled gather sits on a VGPR
// allocator cliff (spills at 150+ regs, or merges burst windows, or melts
// down under sched_barrier). This version changes the DATAFLOW instead:
//  - doc rows staged into LDS COALESCED (lane i reads float4 i of a row;
//    1KB/instr; each L2 line consumed in one burst -> FETCH ~= compulsory)
//  - compute reads rows from LDS; per-thread state is 4 acc + ss (~36 VGPR,
//    structurally spill-proof)
// Layout: wave w owns q 4w..4w+3; lane = (row r=lane&31, half h=lane>>5);
// k = 2*kk+h interleaved (uniform 37-iter loop, one masked tail for h==0);
// pair-combine via shfl_xor(32). LDS 60.5KB -> 2 blocks/CU; 2048 blocks ->
// staging of one block overlaps compute of the co-resident one.
__global__ __launch_bounds__(256, 2) void drmm_main(
    const int* __restrict__ doc, const float* __restrict__ emb,
    const float* __restrict__ qn, int* __restrict__ hist)
{
    __shared__ __align__(16) float4 ds[TR * PITCH];   // 39424 B
    __shared__ __align__(16) float4 qs4[Q_ * EF4];    // 19200 B
    __shared__ int whist[Q_ * NB];                    // 1920 B

    const int tid = threadIdx.x;
    // XCD-grouped decode: xcd = blk&7 hosts batches {xcd, 8+xcd, 16+xcd, 24+xcd}
    const int blk = blockIdx.x;                       // 0..2047
    const int xcd = blk & 7;
    const int j   = blk >> 3;                         // 0..255
    const int b   = ((j & 3) << 3) | xcd;             // 0..31
    const int tile = j >> 2;                          // 0..63
    const int lane = tid & 63, w = tid >> 6;

    // stage qn (coalesced) + zero whist
    const float4* qb = (const float4*)(qn + (size_t)b * Q_ * E_);
    for (int i = tid; i < Q_ * EF4; i += 256) qs4[i] = qb[i];
    for (int i = tid; i < Q_ * NB; i += 256) whist[i] = 0;

    // stage 32 doc rows, 8 per wave, coalesced (each row fetched once/block)
    const int rowbase = b * D_ + tile * TR;
    #pragma unroll 2
    for (int i = 0; i < 8; ++i) {
        const int r = w * 8 + i;
        const int rid = doc[rowbase + r];
        const float4* g4 = (const float4*)(emb + (long long)(rid > 0 ? rid : 0) * E_);
        ds[r * PITCH + lane] = g4[lane];                      // granules 0-63
        if (lane < EF4 - 64) ds[r * PITCH + 64 + lane] = g4[64 + lane]; // 64-74
    }
    __syncthreads();

    // compute: lane -> (row r, half h); wave w -> q 4w..4w+3
    const int r = lane & 31, h = lane >> 5;
    const int rid = doc[rowbase + r];
    const float4* drow = ds + r * PITCH;
    const float4* qA = qs4 + (w * 4 + 0) * EF4;
    const float4* qB = qs4 + (w * 4 + 1) * EF4;
    const float4* qC = qs4 + (w * 4 + 2) * EF4;
    const float4* qD = qs4 + (w * 4 + 3) * EF4;

    float a0 = 0.f, a1 = 0.f, a2 = 0.f, a3 = 0.f, ss = 0.f;
    // k = 2*kk + h: h=0 covers even k 0..72 (+ tail 74), h=1 covers odd 1..73
    for (int kk = 0; kk < 37; ++kk) {
        const int k = 2 * kk + h;
        const float4 d = drow[k];
        ss = fmaf(d.x, d.x, fmaf(d.y, d.y, fmaf(d.z, d.z, fmaf(d.w, d.w, ss))));
        float4 u;
        u = qA[k]; a0 = fmaf(d.x,u.x, fmaf(d.y,u.y, fmaf(d.z,u.z, fmaf(d.w,u.w, a0))));
        u = qB[k]; a1 = fmaf(d.x,u.x, fmaf(d.y,u.y, fmaf(d.z,u.z, fmaf(d.w,u.w, a1))));
        u = qC[k]; a2 = fmaf(d.x,u.x, fmaf(d.y,u.y, fmaf(d.z,u.z, fmaf(d.w,u.w, a2))));
        u = qD[k]; a3 = fmaf(d.x,u.x, fmaf(d.y,u.y, fmaf(d.z,u.z, fmaf(d.w,u.w, a3))));
    }
    if (h == 0) {                            // tail k = 74
        const float4 d = drow[74];
        ss = fmaf(d.x, d.x, fmaf(d.y, d.y, fmaf(d.z, d.z, fmaf(d.w, d.w, ss))));
        float4 u;
        u = qA[74]; a0 = fmaf(d.x,u.x, fmaf(d.y,u.y, fmaf(d.z,u.z, fmaf(d.w,u.w, a0))));
        u = qB[74]; a1 = fmaf(d.x,u.x, fmaf(d.y,u.y, fmaf(d.z,u.z, fmaf(d.w,u.w, a1))));
        u = qC[74]; a2 = fmaf(d.x,u.x, fmaf(d.y,u.y, fmaf(d.z,u.z, fmaf(d.w,u.w, a2))));
        u = qD[74]; a3 = fmaf(d.x,u.x, fmaf(d.y,u.y, fmaf(d.z,u.z, fmaf(d.w,u.w, a3))));
    }

    // pair-combine the two k-halves
    a0 += __shfl_xor(a0, 32);
    a1 += __shfl_xor(a1, 32);
    a2 += __shfl_xor(a2, 32);
    a3 += __shfl_xor(a3, 32);
    ss += __shfl_xor(ss, 32);

    if (h == 0) {                            // 32 lanes bin 4 q's each
        const float rn = 1.0f / sqrtf(ss);   // ss==0 -> inf -> NaN sims -> dropped
        const bool rok = (rid > 0);
        const int qbase = w * 4;
        float xs[4] = {a0 * rn, a1 * rn, a2 * rn, a3 * rn};
        #pragma unroll
        for (int qq = 0; qq < 4; ++qq) {
            const float x = xs[qq];          // NaN (masked q / masked row) dropped
            const float t = (x + 1.0f) * (NB * 0.5f);
            int bin = (int)floorf(t);
            bin = bin < 0 ? 0 : (bin > NB - 1 ? NB - 1 : bin);
            if (rok && x >= -1.0f && x <= 1.0f)
                atomicAdd(&whist[(qbase + qq) * NB + bin], 1);
        }
    }
    __syncthreads();

    // flush block histogram to global
    for (int i = tid; i < Q_ * NB; i += 256) {
        const int v = whist[i];
        if (v) atomicAdd(&hist[b * Q_ * NB + i], v);
    }
}

// ---------------- Kernel 3: log1p + FFN + gated sum ----------------
__global__ __launch_bounds__(64) void drmm_final(
    const int* __restrict__ hist, const float* __restrict__ gbuf,
    const int* __restrict__ query,
    const float* __restrict__ W1, const float* __restrict__ b1,
    const float* __restrict__ W2, const float* __restrict__ b2,
    const float* __restrict__ W3, const float* __restrict__ b3,
    float* __restrict__ out)
{
    const int b = blockIdx.x, lane = threadIdx.x;
    float z = 0.f, e = 0.f;
    if (lane < Q_) {
        const int* h = hist + (b * Q_ + lane) * NB;
        float pre1[5];
        #pragma unroll
        for (int u = 0; u < 5; ++u) pre1[u] = b1[u];
        #pragma unroll
        for (int k = 0; k < NB; ++k) {
            const float hv = fast_log1p((float)h[k]);
            #pragma unroll
            for (int u = 0; u < 5; ++u) pre1[u] = fmaf(hv, W1[k * 5 + u], pre1[u]);
        }
        float z2 = b2[0];
        #pragma unroll
        for (int u = 0; u < 5; ++u) z2 = fmaf(fast_tanh(pre1[u]), W2[u], z2);
        const float z3 = fmaf(fast_tanh(z2), W3[0], b3[0]);
        z = fast_tanh(z3);
        const int id = query[b * Q_ + lane];
        const float g = gbuf[b * Q_ + lane];
        e = (id > 0) ? __expf(g) : 0.f;
    }
    float ze = z * e, se = e;
    #pragma unroll
    for (int off = 32; off > 0; off >>= 1) {
        ze += __shfl_xor(ze, off);
        se += __shfl_xor(se, off);
    }
    if (lane == 0) out[b] = ze / (se + 1e-5f);
}

// ---------------- launch ----------------
extern "C" void kernel_launch(void* const* d_in, const int* in_sizes, int n_in,
                              void* d_out, int out_size, void* d_ws, size_t ws_size,
                              hipStream_t stream)
{
    const int*   query = (const int*)d_in[0];
    const int*   doc   = (const int*)d_in[1];
    // d_in[2] = q_idf (unused by reference)
    const float* emb   = (const float*)d_in[3];
    const float* W1    = (const float*)d_in[4];
    const float* b1    = (const float*)d_in[5];
    const float* W2    = (const float*)d_in[6];
    const float* b2    = (const float*)d_in[7];
    const float* W3    = (const float*)d_in[8];
    const float* b3    = (const float*)d_in[9];
    const float* Wg    = (const float*)d_in[10];
    const float* bg    = (const float*)d_in[11];
    float* out = (float*)d_out;

    // workspace layout
    char* ws = (char*)d_ws;
    float* qn   = (float*)ws;                        // 512*300 f32 = 614400 B
    float* gbuf = (float*)(ws + 614400);             // 512 f32    = 2048 B
    int*   hist = (int*)(ws + 614400 + 2048);        // 15360 ints = 61440 B

    drmm_prep<<<B_, 256, 0, stream>>>(query, emb, Wg, bg, qn, gbuf, hist);
    drmm_main<<<B_ * TPB, 256, 0, stream>>>(doc, emb, qn, hist);
    drmm_final<<<B_, 64, 0, stream>>>(hist, gbuf, query,
                                      W1, b1, W2, b2, W3, b3, out);
}

// Round 13
// 49.383 us; speedup vs baseline: 2.3334x; 1.4193x over previous
//
#include <hip/hip_runtime.h>

#define B_ 32
#define Q_ 16
#define D_ 2048
#define E_ 300
#define EF4 75              // float4 granules per embedding row
#define NB 30
#define TR 64               // doc rows per block (lane = row)
#define PITCH 75            // LDS granules per row; (3r+k)%8 spreads bank-quads
#define TPB (D_ / TR)       // 32 tiles per batch

// Hardware-TRANS-pipe transcendentals (R2: ocml tanhf/log1pf left final 99% stalled)
__device__ __forceinline__ float fast_tanh(float x) {
    const float t = __expf(-2.0f * fabsf(x));
    const float r = (1.0f - t) / (1.0f + t);
    return copysignf(r, x);
}
__device__ __forceinline__ float fast_log1p(float x) { return __logf(1.0f + x); }

// async global->LDS, 16B per lane: LDS dest = wave-uniform base + lane*16,
// global src per-lane. No VGPR round trip (m97 lever).
__device__ __forceinline__ void gload_lds16(const float4* g, float4* l) {
    __builtin_amdgcn_global_load_lds(
        (const __attribute__((address_space(1))) void*)g,
        (__attribute__((address_space(3))) void*)l, 16, 0, 0);
}

// ---------------- Kernel 1: query prep (qn, gate logits) + hist zero ----------------
__global__ __launch_bounds__(256) void drmm_prep(
    const int* __restrict__ query, const float* __restrict__ emb,
    const float* __restrict__ Wg, const float* __restrict__ bg,
    float* __restrict__ qn, float* __restrict__ gbuf, int* __restrict__ hist)
{
    const int b = blockIdx.x, tid = threadIdx.x;
    const int wid = tid >> 6, lane = tid & 63;

    for (int i = b * 256 + tid; i < B_ * Q_ * NB; i += B_ * 256) hist[i] = 0;

    for (int qq = wid; qq < Q_; qq += 4) {
        const int id = query[b * Q_ + qq];
        const float m = (id > 0) ? 1.f : 0.f;
        const float* row = emb + (long long)((id > 0) ? id : 0) * E_;
        float v[5];
        float ss = 0.f, dg = 0.f;
        #pragma unroll
        for (int k = 0; k < 5; ++k) {
            const int e = lane + 64 * k;
            float x = 0.f, w = 0.f;
            if (e < E_) { x = row[e] * m; w = Wg[e]; }
            v[k] = x;
            ss = fmaf(x, x, ss);
            dg = fmaf(x, w, dg);
        }
        #pragma unroll
        for (int off = 32; off > 0; off >>= 1) {
            ss += __shfl_xor(ss, off);
            dg += __shfl_xor(dg, off);
        }
        // masked row: ss==0 -> rn=inf -> qn = 0*inf = NaN (matches reference 0/0)
        const float rn = 1.0f / sqrtf(ss);
        #pragma unroll
        for (int k = 0; k < 5; ++k) {
            const int e = lane + 64 * k;
            if (e < E_) qn[((size_t)(b * Q_ + qq)) * E_ + e] = v[k] * rn;
        }
        if (lane == 0) gbuf[b * Q_ + qq] = fast_tanh(dg + bg[0]);
    }
}

// ---------------- Kernel 2: interaction dots + histogram ----------------
// R12 post-mortem: 5 ds_read_b128 per 20 FMA made the shared DS pipe the
// bottleneck (60 cyc DS vs 10 cyc VALU-equiv per wave-iter), and q-LDS-staging
// was pure overhead (each wave reads each q granule exactly once). Restructure:
//  - lane = row (TR=64), k uniform across the wave -> q[k] addresses are
//    wave-uniform (w via readfirstlane) -> s_load through SMEM/K$ (scalar
//    pipe, L2-resident 77KB/XCD); FMA uses the SGPR operand directly.
//    DS pipe now carries ONE ds_read_b128 per iter (the d row granule).
//  - no cross-lane reduction at all: each lane owns a full row; wave w bins
//    its 4 q's for all 64 rows.
//  - staging via async global_load_lds (16B/lane, 32 in flight per wave,
//    no VGPR round trip) -> fixes R12's 574 GB/s dependent-chain staging.
__global__ __launch_bounds__(256, 2) void drmm_main(
    const int* __restrict__ doc, const float* __restrict__ emb,
    const float* __restrict__ qn, int* __restrict__ hist)
{
    __shared__ __align__(16) float4 ds[TR * PITCH];   // 76800 B
    __shared__ int whist[Q_ * NB];                    // 1920 B

    const int tid = threadIdx.x;
    // XCD-grouped decode: xcd = blk&7 hosts batches {xcd, 8+xcd, 16+xcd, 24+xcd}
    const int blk = blockIdx.x;                       // 0..1023
    const int xcd = blk & 7;
    const int j   = blk >> 3;                         // 0..127
    const int b   = ((j & 3) << 3) | xcd;             // 0..31
    const int tile = j >> 2;                          // 0..31
    const int lane = tid & 63;
    const int w = __builtin_amdgcn_readfirstlane(tid >> 6);

    for (int i = tid; i < Q_ * NB; i += 256) whist[i] = 0;

    const int rowbase = b * D_ + tile * TR;

    // stage 64 rows (16 per wave), async DMA, coalesced 16B/lane
    #pragma unroll
    for (int i = 0; i < 16; ++i) {
        const int r = w * 16 + i;
        const int rid = doc[rowbase + r];             // wave-uniform -> s_load
        const float4* g4 = (const float4*)(emb + (long long)(rid > 0 ? rid : 0) * E_);
        gload_lds16(g4 + lane, &ds[r * PITCH]);                    // granules 0-63
        if (lane < EF4 - 64) gload_lds16(g4 + 64 + lane, &ds[r * PITCH + 64]); // 64-74
    }
    __syncthreads();    // compiler drains vmcnt before the barrier

    // compute: lane = row; wave w owns q 4w..4w+3 (k wave-uniform -> q via SMEM)
    const int rid = doc[rowbase + lane];
    const float4* drow = ds + lane * PITCH;
    const size_t qoff = (size_t)b * Q_ * E_ + (size_t)(w * 4) * E_;
    const float4* q0 = (const float4*)(qn + qoff);
    const float4* q1 = (const float4*)(qn + qoff + E_);
    const float4* q2 = (const float4*)(qn + qoff + 2 * E_);
    const float4* q3 = (const float4*)(qn + qoff + 3 * E_);

    float a0 = 0.f, a1 = 0.f, a2 = 0.f, a3 = 0.f, ss = 0.f;
    #pragma unroll 3
    for (int k = 0; k < EF4; ++k) {
        const float4 d = drow[k];                     // the one DS read
        ss = fmaf(d.x, d.x, fmaf(d.y, d.y, fmaf(d.z, d.z, fmaf(d.w, d.w, ss))));
        float4 u;
        u = q0[k]; a0 = fmaf(d.x,u.x, fmaf(d.y,u.y, fmaf(d.z,u.z, fmaf(d.w,u.w, a0))));
        u = q1[k]; a1 = fmaf(d.x,u.x, fmaf(d.y,u.y, fmaf(d.z,u.z, fmaf(d.w,u.w, a1))));
        u = q2[k]; a2 = fmaf(d.x,u.x, fmaf(d.y,u.y, fmaf(d.z,u.z, fmaf(d.w,u.w, a2))));
        u = q3[k]; a3 = fmaf(d.x,u.x, fmaf(d.y,u.y, fmaf(d.z,u.z, fmaf(d.w,u.w, a3))));
    }

    const float rn = 1.0f / sqrtf(ss);   // NaN q rows / garbage masked rows dropped below
    const bool rok = (rid > 0);
    const int qb = w * 4;
    #define BIN1(X, QI) { const float x_ = (X); \
        const float t_ = (x_ + 1.0f) * (NB * 0.5f); \
        int bin_ = (int)floorf(t_); \
        bin_ = bin_ < 0 ? 0 : (bin_ > NB - 1 ? NB - 1 : bin_); \
        if (rok && x_ >= -1.0f && x_ <= 1.0f) atomicAdd(&whist[(QI) * NB + bin_], 1); }
    BIN1(a0 * rn, qb + 0)
    BIN1(a1 * rn, qb + 1)
    BIN1(a2 * rn, qb + 2)
    BIN1(a3 * rn, qb + 3)
    #undef BIN1
    __syncthreads();

    // flush block histogram to global
    for (int i = tid; i < Q_ * NB; i += 256) {
        const int v = whist[i];
        if (v) atomicAdd(&hist[b * Q_ * NB + i], v);
    }
}

// ---------------- Kernel 3: log1p + FFN + gated sum ----------------
__global__ __launch_bounds__(64) void drmm_final(
    const int* __restrict__ hist, const float* __restrict__ gbuf,
    const int* __restrict__ query,
    const float* __restrict__ W1, const float* __restrict__ b1,
    const float* __restrict__ W2, const float* __restrict__ b2,
    const float* __restrict__ W3, const float* __restrict__ b3,
    float* __restrict__ out)
{
    const int b = blockIdx.x, lane = threadIdx.x;
    float z = 0.f, e = 0.f;
    if (lane < Q_) {
        const int* h = hist + (b * Q_ + lane) * NB;
        float pre1[5];
        #pragma unroll
        for (int u = 0; u < 5; ++u) pre1[u] = b1[u];
        #pragma unroll
        for (int k = 0; k < NB; ++k) {
            const float hv = fast_log1p((float)h[k]);
            #pragma unroll
            for (int u = 0; u < 5; ++u) pre1[u] = fmaf(hv, W1[k * 5 + u], pre1[u]);
        }
        float z2 = b2[0];
        #pragma unroll
        for (int u = 0; u < 5; ++u) z2 = fmaf(fast_tanh(pre1[u]), W2[u], z2);
        const float z3 = fmaf(fast_tanh(z2), W3[0], b3[0]);
        z = fast_tanh(z3);
        const int id = query[b * Q_ + lane];
        const float g = gbuf[b * Q_ + lane];
        e = (id > 0) ? __expf(g) : 0.f;
    }
    float ze = z * e, se = e;
    #pragma unroll
    for (int off = 32; off > 0; off >>= 1) {
        ze += __shfl_xor(ze, off);
        se += __shfl_xor(se, off);
    }
    if (lane == 0) out[b] = ze / (se + 1e-5f);
}

// ---------------- launch ----------------
extern "C" void kernel_launch(void* const* d_in, const int* in_sizes, int n_in,
                              void* d_out, int out_size, void* d_ws, size_t ws_size,
                              hipStream_t stream)
{
    const int*   query = (const int*)d_in[0];
    const int*   doc   = (const int*)d_in[1];
    // d_in[2] = q_idf (unused by reference)
    const float* emb   = (const float*)d_in[3];
    const float* W1    = (const float*)d_in[4];
    const float* b1    = (const float*)d_in[5];
    const float* W2    = (const float*)d_in[6];
    const float* b2    = (const float*)d_in[7];
    const float* W3    = (const float*)d_in[8];
    const float* b3    = (const float*)d_in[9];
    const float* Wg    = (const float*)d_in[10];
    const float* bg    = (const float*)d_in[11];
    float* out = (float*)d_out;

    // workspace layout
    char* ws = (char*)d_ws;
    float* qn   = (float*)ws;                        // 512*300 f32 = 614400 B
    float* gbuf = (float*)(ws + 614400);             // 512 f32    = 2048 B
    int*   hist = (int*)(ws + 614400 + 2048);        // 15360 ints = 61440 B

    drmm_prep<<<B_, 256, 0, stream>>>(query, emb, Wg, bg, qn, gbuf, hist);
    drmm_main<<<B_ * TPB, 256, 0, stream>>>(doc, emb, qn, hist);
    drmm_final<<<B_, 64, 0, stream>>>(hist, gbuf, query,
                                      W1, b1, W2, b2, W3, b3, out);
}